// Round 15
// baseline (428.587 us; speedup 1.0000x reference)
//
#include <hip/hip_runtime.h>
#include <cstdint>
#include <cstddef>

typedef unsigned int u32;
typedef unsigned short u16;
typedef __bf16 bf16x8 __attribute__((ext_vector_type(8)));
typedef float f32x4 __attribute__((ext_vector_type(4)));
typedef u16 u16x8 __attribute__((ext_vector_type(8)));

static constexpr int T_TOK = 4096;
static constexpr int HID   = 2048;
static constexpr int INTER = 1024;
static constexpr int NEXP  = 8;
static constexpr int TOPK  = 2;
static constexpr int SLOT_CAP = 10240;   // 8192 real + per-expert 256-align pad
static constexpr int NT_M = 40;

// meta int indices
static constexpr int M_TOT    = 16;
static constexpr int M_CUR    = 17;    // 8 router cursors
static constexpr int M_DONE   = 40;    // 40 per-mt done counters
static constexpr int M_TOK    = 96;    // toklist[SLOT_CAP] (slot -> t*2+k)
static constexpr int M_SLOTOF = 96 + SLOT_CAP;  // slotof[T*K] (t*2+k -> slot)

__device__ __forceinline__ u16 f2bf(float f) {
  u32 u = __builtin_bit_cast(u32, f);
  u32 r = (u + 0x7fffu + ((u >> 16) & 1u)) >> 16;
  return (u16)r;
}
__device__ __forceinline__ float bf2f(u16 h) {
  return __builtin_bit_cast(float, (u32)h << 16);
}

// RELAXED poll + one acquire fence after success (R11-validated).
__device__ __forceinline__ void spin_ge(int* p, int target) {
  while (__hip_atomic_load(p, __ATOMIC_RELAXED, __HIP_MEMORY_SCOPE_AGENT) < target)
    __builtin_amdgcn_s_sleep(8);
  __builtin_amdgcn_fence(__ATOMIC_ACQUIRE, "agent");
}
// stores done -> __syncthreads() (drains all waves' vmcnt) -> tid0 release RMW.
__device__ __forceinline__ void bump(int* p, int tid) {
  __syncthreads();
  if (tid == 0)
    __hip_atomic_fetch_add(p, 1, __ATOMIC_RELEASE, __HIP_MEMORY_SCOPE_AGENT);
}

// ---------------- router ----------------
__global__ void router_count(const int* __restrict__ eidx, int* __restrict__ meta) {
  __shared__ int cnt[NEXP];
  const int tid = threadIdx.x;
  if (tid < NEXP) cnt[tid] = 0;
  __syncthreads();
  for (int i = tid; i < T_TOK * TOPK; i += 256) atomicAdd(&cnt[eidx[i]], 1);
  __syncthreads();
  if (tid == 0) {
    int off = 0;
    for (int e = 0; e < NEXP; ++e) {
      int c = cnt[e];
      meta[e] = c;
      meta[8 + e] = off;
      meta[M_CUR + e] = off;
      off += (c + 255) & ~255;      // 256-aligned regions (BM=256)
    }
    meta[M_TOT] = off;
  }
}

__global__ void init_k(int* __restrict__ meta) {
  const int i = blockIdx.x * 256 + threadIdx.x;
  if (i < SLOT_CAP) meta[M_TOK + i] = 0;   // pad slots nominally token 0
  if (i >= 25 && i < 80) meta[i] = 0;      // DONE[40] etc.
}

__global__ void router_assign(const int* __restrict__ eidx, int* __restrict__ meta) {
  const int t = blockIdx.x * 256 + threadIdx.x;
  if (t >= T_TOK) return;
  int* cursors = meta + M_CUR;
  int* toklist = meta + M_TOK;
  int* slotof  = meta + M_SLOTOF;
  for (int k = 0; k < TOPK; ++k) {
    const int e = eidx[t * TOPK + k];
    const int pos = atomicAdd(&cursors[e], 1);
    toklist[pos] = t * 2 + k;
    slotof[t * 2 + k] = pos;
  }
}

// ---------------- x scatter: one block per token, write bf16 row to both slots ----------------
// Reads x exactly once (33.5MB), writes 42MB. Pad slots stay unwritten: garbage
// there is row-isolated through both MFMAs (row r of D depends only on row r of A)
// and never read by combine -> output-deterministic.
__global__ void xprep_k(const float* __restrict__ x, const int* __restrict__ meta,
                        u16* __restrict__ xs) {
  const int t = blockIdx.x;
  const int col = threadIdx.x * 8;
  const float* src = x + (size_t)t * HID + col;
  const float4 a = *(const float4*)src;
  const float4 b = *(const float4*)(src + 4);
  u16x8 o;
  o[0] = f2bf(a.x); o[1] = f2bf(a.y); o[2] = f2bf(a.z); o[3] = f2bf(a.w);
  o[4] = f2bf(b.x); o[5] = f2bf(b.y); o[6] = f2bf(b.z); o[7] = f2bf(b.w);
  const int s0 = meta[M_SLOTOF + 2 * t];
  const int s1 = meta[M_SLOTOF + 2 * t + 1];
  *(u16x8*)(xs + (size_t)s0 * HID + col) = o;
  *(u16x8*)(xs + (size_t)s1 * HID + col) = o;
}

// ---------------- 256x256 GEMM tile body: fused int4-dequant B-staging ----------------
// C[slot, n] = sum_k A[slot0+r, k] * B[n, k]. B comes DIRECTLY from packed int4
// weights (1 int32 = 2 cols = bf16-equal bytes): per thread per K-tile, 4 chunks of
// {int4 global load (8 cols packed) + 1 scale + dequant + ds_write_b128} at the
// SAME logical(r,cb)->linear-LDS mapping as the pre-swizzled global_load_lds
// (stored offset = linear D, content = unswizzled element) -> COMPUTE unchanged.
// GROUP=32 aligns with the subtile col-half (S&1) -> exactly one scale per chunk.
// A (bf16 activations: xs for G1, hbuf for G2) keeps global_load_lds staging.
// Swizzle o^=((o>>7)&3)<<4 (PMC-verified conflict-free). BM=BN=256, BK=64,
// 8 waves (2M x 4N), wave tile 128x64, dbuf LDS 2x64KB.
// G1M: gate|up B-row interleave + fused silu(gate)*up epilogue into hbuf.
// !G1M: slot-major contiguous writes into ys (aliases xs; rows dead by gating).
template <int KT, bool G1M>
__device__ void gemm_body(const u16* __restrict__ A, const int* __restrict__ Wp,
                          const float* __restrict__ Ws, u16* __restrict__ Cout,
                          u16* lds, int slot0, int nt, int tid) {
  static constexpr int NT = KT / 64;
  char* ldsB = (char*)lds;

  const u16* asrc[4];
  const int4* bpk[4];
  const float* bsp[4];
  int bdst[4];
#pragma unroll
  for (int j = 0; j < 4; ++j) {
    const int L = j * 8192 + tid * 16;
    const int S = L >> 10;
    int o = L & 1023;
    o ^= ((o >> 7) & 3) << 4;
    const int r = (S >> 1) * 16 + (o >> 6);     // panel row 0..255
    const int cb = (S & 1) * 64 + (o & 63);     // col-byte 0..127 (bf16)
    asrc[j] = A + (size_t)(slot0 + r) * KT + (cb >> 1);
    int brow;
    if (G1M) {
      const int g = r >> 6, j6 = r & 63;
      brow = nt * 128 + g * 32 + (j6 & 31) + ((j6 >> 5) << 10);  // gate | up+1024
    } else {
      brow = nt * 256 + r;
    }
    bpk[j] = (const int4*)(Wp + (size_t)brow * (KT / 2) + (cb >> 2));
    bsp[j] = Ws + (size_t)brow * (KT / 32) + (S & 1);
    bdst[j] = 32768 + L;
  }

#define STAGE_A(kt_, c_)                                                              \
  do {                                                                                \
    _Pragma("unroll") for (int j = 0; j < 4; ++j)                                     \
        __builtin_amdgcn_global_load_lds(                                             \
            (const __attribute__((address_space(1))) void*)(asrc[j] + (kt_) * 64),    \
            (__attribute__((address_space(3))) void*)(ldsB + (c_) * 65536 +           \
                                                     j * 8192 + tid * 16),            \
            16, 0, 0);                                                                \
  } while (0)

  int4 pk0, pk1, pk2, pk3;
  float sc0, sc1, sc2, sc3;
#define B_LOAD(kt_)                                                                   \
  do {                                                                               \
    pk0 = bpk[0][(kt_) * 8]; sc0 = bsp[0][(kt_) * 2];                                \
    pk1 = bpk[1][(kt_) * 8]; sc1 = bsp[1][(kt_) * 2];                                \
    pk2 = bpk[2][(kt_) * 8]; sc2 = bsp[2][(kt_) * 2];                                \
    pk3 = bpk[3][(kt_) * 8]; sc3 = bsp[3][(kt_) * 2];                                \
  } while (0)

#define BW1(c_, pk_, sc_, j_)                                                         \
  do {                                                                               \
    const int v_[4] = {pk_.x, pk_.y, pk_.z, pk_.w};                                  \
    u16x8 q_;                                                                        \
    _Pragma("unroll") for (int b = 0; b < 4; ++b) {                                  \
      q_[2 * b]     = f2bf((float)((v_[b] & 15) - 8) * sc_);                         \
      q_[2 * b + 1] = f2bf((float)(((v_[b] >> 4) & 15) - 8) * sc_);                  \
    }                                                                                \
    *(u16x8*)(ldsB + (c_) * 65536 + bdst[j_]) = q_;                                  \
  } while (0)
#define B_WRITE(c_)                                                                   \
  do { BW1(c_, pk0, sc0, 0); BW1(c_, pk1, sc1, 1);                                   \
       BW1(c_, pk2, sc2, 2); BW1(c_, pk3, sc3, 3); } while (0)

  const int lane = tid & 63;
  const int wid = tid >> 6;
  const int wm = (wid >> 2) * 128;
  const int wn = (wid & 3) * 64;
  const int fr = lane & 15;
  const int qq = lane >> 4;
  const int swz = (qq * 16) ^ (((fr >> 1) & 3) << 4);

  const int abase = (wm >> 4) * 2048 + fr * 64 + swz;
  const int bbase = 32768 + (wn >> 4) * 2048 + fr * 64 + swz;

  f32x4 acc[8][4];
#pragma unroll
  for (int m = 0; m < 8; ++m)
#pragma unroll
    for (int n = 0; n < 4; ++n) acc[m][n] = (f32x4)0.0f;

#define COMPUTE(c_)                                                                   \
  do {                                                                                \
    const char* bb_ = ldsB + (c_) * 65536;                                            \
    bf16x8 bfr_[4][2];                                                                \
    _Pragma("unroll") for (int nf = 0; nf < 4; ++nf)                                  \
        _Pragma("unroll") for (int ks = 0; ks < 2; ++ks)                              \
            bfr_[nf][ks] = *(const bf16x8*)(bb_ + bbase + nf * 2048 + ks * 1024);     \
    _Pragma("unroll") for (int mh = 0; mh < 2; ++mh) {                                \
      bf16x8 af_[4][2];                                                               \
      _Pragma("unroll") for (int mf = 0; mf < 4; ++mf)                                \
          _Pragma("unroll") for (int ks = 0; ks < 2; ++ks)                            \
              af_[mf][ks] = *(const bf16x8*)(bb_ + abase + mh * 8192 + mf * 2048 +    \
                                             ks * 1024);                              \
      __builtin_amdgcn_s_setprio(1);                                                  \
      _Pragma("unroll") for (int mf = 0; mf < 4; ++mf)                                \
          _Pragma("unroll") for (int nf = 0; nf < 4; ++nf)                            \
              _Pragma("unroll") for (int ks = 0; ks < 2; ++ks)                        \
                  acc[mh * 4 + mf][nf] = __builtin_amdgcn_mfma_f32_16x16x32_bf16(     \
                      af_[mf][ks], bfr_[nf][ks], acc[mh * 4 + mf][nf], 0, 0, 0);      \
      __builtin_amdgcn_s_setprio(0);                                                  \
    }                                                                                 \
  } while (0)

  // prologue: tile 0 into buf0
  STAGE_A(0, 0);
  B_LOAD(0);
  asm volatile("s_waitcnt vmcnt(0)" ::: "memory");
  __builtin_amdgcn_sched_barrier(0);
  B_WRITE(0);
  asm volatile("s_waitcnt lgkmcnt(0)" ::: "memory");
  __builtin_amdgcn_s_barrier();

#pragma unroll 1
  for (int kt = 0; kt < NT; kt += 2) {
    // even tile (buf0); prefetch kt+1 -> buf1 (buf1 readers finished at prev barrier)
    STAGE_A(kt + 1, 1);
    B_LOAD(kt + 1);
    __builtin_amdgcn_sched_barrier(0);
    COMPUTE(0);
    __builtin_amdgcn_sched_barrier(0);
    asm volatile("s_waitcnt vmcnt(0)" ::: "memory");
    B_WRITE(1);
    asm volatile("s_waitcnt lgkmcnt(0)" ::: "memory");
    __builtin_amdgcn_s_barrier();
    // odd tile (buf1); prefetch kt+2 -> buf0
    if (kt + 2 < NT) {
      STAGE_A(kt + 2, 0);
      B_LOAD(kt + 2);
    }
    __builtin_amdgcn_sched_barrier(0);
    COMPUTE(1);
    __builtin_amdgcn_sched_barrier(0);
    asm volatile("s_waitcnt vmcnt(0)" ::: "memory");
    if (kt + 2 < NT) {
      B_WRITE(0);
      asm volatile("s_waitcnt lgkmcnt(0)" ::: "memory");
    }
    __builtin_amdgcn_s_barrier();
  }
#undef STAGE_A
#undef B_LOAD
#undef BW1
#undef B_WRITE
#undef COMPUTE

  // epilogue: C/D layout col=lane&15, row=(lane>>4)*4+j  [m89-verified]
  if (G1M) {
    const int g = wid & 3;
#pragma unroll
    for (int mi = 0; mi < 8; ++mi)
#pragma unroll
      for (int n = 0; n < 2; ++n)
#pragma unroll
        for (int jj = 0; jj < 4; ++jj) {
          const float gv = acc[mi][n][jj];
          const float uv = acc[mi][n + 2][jj];
          const float hv = gv / (1.0f + __expf(-gv)) * uv;
          const int row = slot0 + wm + mi * 16 + qq * 4 + jj;
          Cout[(size_t)row * INTER + nt * 128 + g * 32 + n * 16 + fr] = f2bf(hv);
        }
  } else {
#pragma unroll
    for (int mi = 0; mi < 8; ++mi)
#pragma unroll
      for (int jj = 0; jj < 4; ++jj) {
        const int row = slot0 + wm + mi * 16 + qq * 4 + jj;
        const int col = nt * 256 + wn + fr;
#pragma unroll
        for (int n = 0; n < 4; ++n)
          Cout[(size_t)row * HID + col + n * 16] = f2bf(acc[mi][n][jj]);
      }
  }
}

// ---------------- static-schedule tile runners ----------------
__device__ __forceinline__ void run_g1(const u16* xs, const int* w1, const float* w1s,
                                       u16* hbuf, int* meta, u16* lds,
                                       int mt, int nt, int tid) {
  const int slot0 = mt * 256;
  if (slot0 < meta[M_TOT]) {
    int e = 0;
#pragma unroll
    for (int i = 1; i < NEXP; ++i) e += (slot0 >= meta[8 + i]);
    gemm_body<2048, true>(xs, w1 + (size_t)e * 2048 * 1024,
                          w1s + (size_t)e * 2048 * 64, hbuf, lds, slot0, nt, tid);
  }
  bump(&meta[M_DONE + mt], tid);   // bump even when skipped so spins reach 8
}

__device__ __forceinline__ void run_g2(const u16* hbuf, const int* w2, const float* w2s,
                                       u16* ys, int* meta, u16* lds,
                                       int mt, int nt, int tid) {
  const int slot0 = mt * 256;
  if (slot0 >= meta[M_TOT]) return;
  int e = 0;
#pragma unroll
  for (int i = 1; i < NEXP; ++i) e += (slot0 >= meta[8 + i]);
  if (tid == 0) spin_ge(&meta[M_DONE + mt], 8);
  __syncthreads();
  gemm_body<1024, false>(hbuf, w2 + (size_t)e * 2048 * 512,
                         w2s + (size_t)e * 2048 * 32, ys, lds, slot0, nt, tid);
}

// ---------------- static overlapped GEMM kernel (256 blocks, R11 schedule) ----------------
// G1 round 1: block b -> (mt=b%32, nt=b/32); same-mt blocks on XCD mt%8 (xs local).
// G1 round 2: blocks 0..63 -> (mt=32+b%8, nt=b/8).
// G2: blocks 64..255 take the 256 tiles of mts 0..31 (mt%8==b%8 keeps hbuf
//     L2-local); blocks 0..63 take G2 of mts 32..39 after their own G1.
__global__ __launch_bounds__(512, 2) void gemm_static(
    const u16* __restrict__ xs, const int* __restrict__ w1,
    const float* __restrict__ w1s, const int* __restrict__ w2,
    const float* __restrict__ w2s, u16* __restrict__ hbuf, u16* __restrict__ ys,
    int* __restrict__ meta) {
  __shared__ u16 lds[2 * 32768];
  const int tid = threadIdx.x;
  const int b = blockIdx.x;

  run_g1(xs, w1, w1s, hbuf, meta, lds, b & 31, b >> 5, tid);
  if (b < 64) {
    run_g1(xs, w1, w1s, hbuf, meta, lds, 32 + (b & 7), b >> 3, tid);
    run_g2(hbuf, w2, w2s, ys, meta, lds, 32 + (b & 7), b >> 3, tid);
  } else {
    const int x = b & 7, q = (b - 64) >> 3;   // q in 0..23
    {
      const int k = q;
      run_g2(hbuf, w2, w2s, ys, meta, lds, x + 8 * (k & 3), k >> 2, tid);
    }
    if (q < 8) {
      const int k = q + 24;
      run_g2(hbuf, w2, w2s, ys, meta, lds, x + 8 * (k & 3), k >> 2, tid);
    }
  }
}

// ---------------- combine (slot-major ys via slotof) ----------------
__global__ void combine_k(const u16* __restrict__ ys, const float* __restrict__ ew,
                          const int* __restrict__ meta, float* __restrict__ out) {
  const int idx = blockIdx.x * 256 + threadIdx.x;
  const int t = idx >> 8;
  const int pos = (idx & 255) * 8;
  const int* slotof = meta + M_SLOTOF;
  const int s0 = slotof[t * 2];
  const int s1 = slotof[t * 2 + 1];
  const float w0 = ew[t * 2];
  const float w1 = ew[t * 2 + 1];
  const u16x8 v0 = *(const u16x8*)(ys + (size_t)s0 * HID + pos);
  const u16x8 v1 = *(const u16x8*)(ys + (size_t)s1 * HID + pos);
  float* dst = out + (size_t)t * HID + pos;
  float4 o0, o1;
  o0.x = w0 * bf2f(v0[0]) + w1 * bf2f(v1[0]);
  o0.y = w0 * bf2f(v0[1]) + w1 * bf2f(v1[1]);
  o0.z = w0 * bf2f(v0[2]) + w1 * bf2f(v1[2]);
  o0.w = w0 * bf2f(v0[3]) + w1 * bf2f(v1[3]);
  o1.x = w0 * bf2f(v0[4]) + w1 * bf2f(v1[4]);
  o1.y = w0 * bf2f(v0[5]) + w1 * bf2f(v1[5]);
  o1.z = w0 * bf2f(v0[6]) + w1 * bf2f(v1[6]);
  o1.w = w0 * bf2f(v0[7]) + w1 * bf2f(v1[7]);
  *(float4*)dst = o0;
  *(float4*)(dst + 4) = o1;
}

// ---------------- launch ----------------
extern "C" void kernel_launch(void* const* d_in, const int* in_sizes, int n_in,
                              void* d_out, int out_size, void* d_ws, size_t ws_size,
                              hipStream_t stream) {
  const float* x    = (const float*)d_in[0];
  const int*   w1   = (const int*)d_in[1];
  const float* w1s  = (const float*)d_in[2];
  const int*   w2   = (const int*)d_in[3];
  const float* w2s  = (const float*)d_in[4];
  const float* ew   = (const float*)d_in[5];
  const int*   eidx = (const int*)d_in[6];
  float* out = (float*)d_out;

  char* ws = (char*)d_ws;
  const size_t OFF_XS   = 0;          // 10240*2048*2 = 41,943,040 (xs; ys aliases)
  const size_t OFF_H    = 41943040;   // 10240*1024*2 = 20,971,520
  const size_t OFF_META = 62914560;   // pad 131,072
  const size_t NEED     = 63045632;   // far below proven-available ws
  if (ws_size < NEED) return;

  u16* xs   = (u16*)(ws + OFF_XS);    // slot-gathered activations; G2 output aliases
  u16* hbuf = (u16*)(ws + OFF_H);
  int* meta = (int*)(ws + OFF_META);

  router_count<<<1, 256, 0, stream>>>(eidx, meta);
  init_k<<<SLOT_CAP / 256, 256, 0, stream>>>(meta);
  router_assign<<<T_TOK / 256, 256, 0, stream>>>(eidx, meta);

  xprep_k<<<T_TOK, 256, 0, stream>>>(x, meta, xs);

  gemm_static<<<256, 512, 0, stream>>>(xs, w1, w1s, w2, w2s, hbuf, xs, meta);

  combine_k<<<(T_TOK * HID) / (256 * 8), 256, 0, stream>>>(xs, ew, meta, out);
}

// Round 16
// 423.455 us; speedup vs baseline: 1.0121x; 1.0121x over previous
//
#include <hip/hip_runtime.h>
#include <cstdint>
#include <cstddef>

typedef unsigned int u32;
typedef unsigned short u16;
typedef __bf16 bf16x8 __attribute__((ext_vector_type(8)));
typedef float f32x4 __attribute__((ext_vector_type(4)));
typedef u16 u16x8 __attribute__((ext_vector_type(8)));

static constexpr int T_TOK = 4096;
static constexpr int HID   = 2048;
static constexpr int INTER = 1024;
static constexpr int NEXP  = 8;
static constexpr int TOPK  = 2;
static constexpr int SLOT_CAP = 10240;   // 8192 real + per-expert 256-align pad
static constexpr int NT_M = 40;

// meta int indices
static constexpr int M_TOT    = 16;
static constexpr int M_CUR    = 17;    // 8 router cursors
static constexpr int M_DONE   = 40;    // 40 per-mt done counters
static constexpr int M_TOK    = 96;    // toklist[SLOT_CAP] (slot -> t*2+k)
static constexpr int M_SLOTOF = 96 + SLOT_CAP;  // slotof[T*K] (t*2+k -> slot)

__device__ __forceinline__ u16 f2bf(float f) {
  u32 u = __builtin_bit_cast(u32, f);
  u32 r = (u + 0x7fffu + ((u >> 16) & 1u)) >> 16;
  return (u16)r;
}
__device__ __forceinline__ float bf2f(u16 h) {
  return __builtin_bit_cast(float, (u32)h << 16);
}

// RELAXED poll + one acquire fence after success (R11-validated).
__device__ __forceinline__ void spin_ge(int* p, int target) {
  while (__hip_atomic_load(p, __ATOMIC_RELAXED, __HIP_MEMORY_SCOPE_AGENT) < target)
    __builtin_amdgcn_s_sleep(8);
  __builtin_amdgcn_fence(__ATOMIC_ACQUIRE, "agent");
}
// stores done -> __syncthreads() (drains all waves' vmcnt) -> tid0 release RMW.
__device__ __forceinline__ void bump(int* p, int tid) {
  __syncthreads();
  if (tid == 0)
    __hip_atomic_fetch_add(p, 1, __ATOMIC_RELEASE, __HIP_MEMORY_SCOPE_AGENT);
}

// ---------------- router ----------------
__global__ void router_count(const int* __restrict__ eidx, int* __restrict__ meta) {
  __shared__ int cnt[NEXP];
  const int tid = threadIdx.x;
  if (tid < NEXP) cnt[tid] = 0;
  __syncthreads();
  for (int i = tid; i < T_TOK * TOPK; i += 256) atomicAdd(&cnt[eidx[i]], 1);
  __syncthreads();
  if (tid == 0) {
    int off = 0;
    for (int e = 0; e < NEXP; ++e) {
      int c = cnt[e];
      meta[e] = c;
      meta[8 + e] = off;
      meta[M_CUR + e] = off;
      off += (c + 255) & ~255;      // 256-aligned regions (BM=256)
    }
    meta[M_TOT] = off;
  }
}

__global__ void init_k(int* __restrict__ meta) {
  const int i = blockIdx.x * 256 + threadIdx.x;
  if (i < SLOT_CAP) meta[M_TOK + i] = 0;   // pad slots nominally token 0
  if (i >= 25 && i < 80) meta[i] = 0;      // DONE[40] etc.
}

__global__ void router_assign(const int* __restrict__ eidx, int* __restrict__ meta) {
  const int t = blockIdx.x * 256 + threadIdx.x;
  if (t >= T_TOK) return;
  int* cursors = meta + M_CUR;
  int* toklist = meta + M_TOK;
  int* slotof  = meta + M_SLOTOF;
  for (int k = 0; k < TOPK; ++k) {
    const int e = eidx[t * TOPK + k];
    const int pos = atomicAdd(&cursors[e], 1);
    toklist[pos] = t * 2 + k;
    slotof[t * 2 + k] = pos;
  }
}

// ---------------- x scatter: one block per token, write bf16 row to both slots ----------------
// Pad slots stay unwritten: garbage there is row-isolated through both MFMAs and
// never read by combine -> output-deterministic.
__global__ void xprep_k(const float* __restrict__ x, const int* __restrict__ meta,
                        u16* __restrict__ xs) {
  const int t = blockIdx.x;
  const int col = threadIdx.x * 8;
  const float* src = x + (size_t)t * HID + col;
  const float4 a = *(const float4*)src;
  const float4 b = *(const float4*)(src + 4);
  u16x8 o;
  o[0] = f2bf(a.x); o[1] = f2bf(a.y); o[2] = f2bf(a.z); o[3] = f2bf(a.w);
  o[4] = f2bf(b.x); o[5] = f2bf(b.y); o[6] = f2bf(b.z); o[7] = f2bf(b.w);
  const int s0 = meta[M_SLOTOF + 2 * t];
  const int s1 = meta[M_SLOTOF + 2 * t + 1];
  *(u16x8*)(xs + (size_t)s0 * HID + col) = o;
  *(u16x8*)(xs + (size_t)s1 * HID + col) = o;
}

// ---------------- 256x256 GEMM tile body: fused int4-dequant B-staging ----------------
// Identical to R15 except the kernel-level launch bounds fix (512,1): LDS (128KB)
// already caps at 1 block/CU, so the (512,2)-induced 128-VGPR cap bought nothing
// and forced pk0..3 to scratch (R15: WRITE_SIZE 407MB). At (512,1) the allocator
// gets 256 VGPRs at the same 8 waves/CU.
// B: per thread per K-tile, 4 chunks {int4 packed load (8 cols) + 1 scale +
// dequant + ds_write_b128} at the same (r,cb)->linear-LDS mapping as the
// pre-swizzled global_load_lds. GROUP=32 aligns with subtile col-half (S&1).
// A keeps global_load_lds. Swizzle o^=((o>>7)&3)<<4 (PMC-verified conflict-free).
template <int KT, bool G1M>
__device__ void gemm_body(const u16* __restrict__ A, const int* __restrict__ Wp,
                          const float* __restrict__ Ws, u16* __restrict__ Cout,
                          u16* lds, int slot0, int nt, int tid) {
  static constexpr int NT = KT / 64;
  char* ldsB = (char*)lds;

  const u16* asrc[4];
  const int4* bpk[4];
  const float* bsp[4];
  int bdst[4];
#pragma unroll
  for (int j = 0; j < 4; ++j) {
    const int L = j * 8192 + tid * 16;
    const int S = L >> 10;
    int o = L & 1023;
    o ^= ((o >> 7) & 3) << 4;
    const int r = (S >> 1) * 16 + (o >> 6);     // panel row 0..255
    const int cb = (S & 1) * 64 + (o & 63);     // col-byte 0..127 (bf16)
    asrc[j] = A + (size_t)(slot0 + r) * KT + (cb >> 1);
    int brow;
    if (G1M) {
      const int g = r >> 6, j6 = r & 63;
      brow = nt * 128 + g * 32 + (j6 & 31) + ((j6 >> 5) << 10);  // gate | up+1024
    } else {
      brow = nt * 256 + r;
    }
    bpk[j] = (const int4*)(Wp + (size_t)brow * (KT / 2) + (cb >> 2));
    bsp[j] = Ws + (size_t)brow * (KT / 32) + (S & 1);
    bdst[j] = 32768 + L;
  }

#define STAGE_A(kt_, c_)                                                              \
  do {                                                                                \
    _Pragma("unroll") for (int j = 0; j < 4; ++j)                                     \
        __builtin_amdgcn_global_load_lds(                                             \
            (const __attribute__((address_space(1))) void*)(asrc[j] + (kt_) * 64),    \
            (__attribute__((address_space(3))) void*)(ldsB + (c_) * 65536 +           \
                                                     j * 8192 + tid * 16),            \
            16, 0, 0);                                                                \
  } while (0)

  int4 pk0, pk1, pk2, pk3;
  float sc0, sc1, sc2, sc3;
#define B_LOAD(kt_)                                                                   \
  do {                                                                               \
    pk0 = bpk[0][(kt_) * 8]; sc0 = bsp[0][(kt_) * 2];                                \
    pk1 = bpk[1][(kt_) * 8]; sc1 = bsp[1][(kt_) * 2];                                \
    pk2 = bpk[2][(kt_) * 8]; sc2 = bsp[2][(kt_) * 2];                                \
    pk3 = bpk[3][(kt_) * 8]; sc3 = bsp[3][(kt_) * 2];                                \
  } while (0)

#define BW1(c_, pk_, sc_, j_)                                                         \
  do {                                                                               \
    const int v_[4] = {pk_.x, pk_.y, pk_.z, pk_.w};                                  \
    u16x8 q_;                                                                        \
    _Pragma("unroll") for (int b = 0; b < 4; ++b) {                                  \
      q_[2 * b]     = f2bf((float)((v_[b] & 15) - 8) * sc_);                         \
      q_[2 * b + 1] = f2bf((float)(((v_[b] >> 4) & 15) - 8) * sc_);                  \
    }                                                                                \
    *(u16x8*)(ldsB + (c_) * 65536 + bdst[j_]) = q_;                                  \
  } while (0)
#define B_WRITE(c_)                                                                   \
  do { BW1(c_, pk0, sc0, 0); BW1(c_, pk1, sc1, 1);                                   \
       BW1(c_, pk2, sc2, 2); BW1(c_, pk3, sc3, 3); } while (0)

  const int lane = tid & 63;
  const int wid = tid >> 6;
  const int wm = (wid >> 2) * 128;
  const int wn = (wid & 3) * 64;
  const int fr = lane & 15;
  const int qq = lane >> 4;
  const int swz = (qq * 16) ^ (((fr >> 1) & 3) << 4);

  const int abase = (wm >> 4) * 2048 + fr * 64 + swz;
  const int bbase = 32768 + (wn >> 4) * 2048 + fr * 64 + swz;

  f32x4 acc[8][4];
#pragma unroll
  for (int m = 0; m < 8; ++m)
#pragma unroll
    for (int n = 0; n < 4; ++n) acc[m][n] = (f32x4)0.0f;

#define COMPUTE(c_)                                                                   \
  do {                                                                                \
    const char* bb_ = ldsB + (c_) * 65536;                                            \
    bf16x8 bfr_[4][2];                                                                \
    _Pragma("unroll") for (int nf = 0; nf < 4; ++nf)                                  \
        _Pragma("unroll") for (int ks = 0; ks < 2; ++ks)                              \
            bfr_[nf][ks] = *(const bf16x8*)(bb_ + bbase + nf * 2048 + ks * 1024);     \
    _Pragma("unroll") for (int mh = 0; mh < 2; ++mh) {                                \
      bf16x8 af_[4][2];                                                               \
      _Pragma("unroll") for (int mf = 0; mf < 4; ++mf)                                \
          _Pragma("unroll") for (int ks = 0; ks < 2; ++ks)                            \
              af_[mf][ks] = *(const bf16x8*)(bb_ + abase + mh * 8192 + mf * 2048 +    \
                                             ks * 1024);                              \
      __builtin_amdgcn_s_setprio(1);                                                  \
      _Pragma("unroll") for (int mf = 0; mf < 4; ++mf)                                \
          _Pragma("unroll") for (int nf = 0; nf < 4; ++nf)                            \
              _Pragma("unroll") for (int ks = 0; ks < 2; ++ks)                        \
                  acc[mh * 4 + mf][nf] = __builtin_amdgcn_mfma_f32_16x16x32_bf16(     \
                      af_[mf][ks], bfr_[nf][ks], acc[mh * 4 + mf][nf], 0, 0, 0);      \
      __builtin_amdgcn_s_setprio(0);                                                  \
    }                                                                                 \
  } while (0)

  // prologue: tile 0 into buf0
  STAGE_A(0, 0);
  B_LOAD(0);
  asm volatile("s_waitcnt vmcnt(0)" ::: "memory");
  __builtin_amdgcn_sched_barrier(0);
  B_WRITE(0);
  asm volatile("s_waitcnt lgkmcnt(0)" ::: "memory");
  __builtin_amdgcn_s_barrier();

#pragma unroll 1
  for (int kt = 0; kt < NT; kt += 2) {
    // even tile (buf0); prefetch kt+1 -> buf1 (buf1 readers done at prev barrier)
    STAGE_A(kt + 1, 1);
    B_LOAD(kt + 1);
    __builtin_amdgcn_sched_barrier(0);
    COMPUTE(0);
    __builtin_amdgcn_sched_barrier(0);
    asm volatile("s_waitcnt vmcnt(0)" ::: "memory");
    B_WRITE(1);
    asm volatile("s_waitcnt lgkmcnt(0)" ::: "memory");
    __builtin_amdgcn_s_barrier();
    // odd tile (buf1); prefetch kt+2 -> buf0
    if (kt + 2 < NT) {
      STAGE_A(kt + 2, 0);
      B_LOAD(kt + 2);
    }
    __builtin_amdgcn_sched_barrier(0);
    COMPUTE(1);
    __builtin_amdgcn_sched_barrier(0);
    asm volatile("s_waitcnt vmcnt(0)" ::: "memory");
    if (kt + 2 < NT) {
      B_WRITE(0);
      asm volatile("s_waitcnt lgkmcnt(0)" ::: "memory");
    }
    __builtin_amdgcn_s_barrier();
  }
#undef STAGE_A
#undef B_LOAD
#undef BW1
#undef B_WRITE
#undef COMPUTE

  // epilogue: C/D layout col=lane&15, row=(lane>>4)*4+j  [m89-verified]
  if (G1M) {
    const int g = wid & 3;
#pragma unroll
    for (int mi = 0; mi < 8; ++mi)
#pragma unroll
      for (int n = 0; n < 2; ++n)
#pragma unroll
        for (int jj = 0; jj < 4; ++jj) {
          const float gv = acc[mi][n][jj];
          const float uv = acc[mi][n + 2][jj];
          const float hv = gv / (1.0f + __expf(-gv)) * uv;
          const int row = slot0 + wm + mi * 16 + qq * 4 + jj;
          Cout[(size_t)row * INTER + nt * 128 + g * 32 + n * 16 + fr] = f2bf(hv);
        }
  } else {
#pragma unroll
    for (int mi = 0; mi < 8; ++mi)
#pragma unroll
      for (int jj = 0; jj < 4; ++jj) {
        const int row = slot0 + wm + mi * 16 + qq * 4 + jj;
        const int col = nt * 256 + wn + fr;
#pragma unroll
        for (int n = 0; n < 4; ++n)
          Cout[(size_t)row * HID + col + n * 16] = f2bf(acc[mi][n][jj]);
      }
  }
}

// ---------------- static-schedule tile runners ----------------
__device__ __forceinline__ void run_g1(const u16* xs, const int* w1, const float* w1s,
                                       u16* hbuf, int* meta, u16* lds,
                                       int mt, int nt, int tid) {
  const int slot0 = mt * 256;
  if (slot0 < meta[M_TOT]) {
    int e = 0;
#pragma unroll
    for (int i = 1; i < NEXP; ++i) e += (slot0 >= meta[8 + i]);
    gemm_body<2048, true>(xs, w1 + (size_t)e * 2048 * 1024,
                          w1s + (size_t)e * 2048 * 64, hbuf, lds, slot0, nt, tid);
  }
  bump(&meta[M_DONE + mt], tid);   // bump even when skipped so spins reach 8
}

__device__ __forceinline__ void run_g2(const u16* hbuf, const int* w2, const float* w2s,
                                       u16* ys, int* meta, u16* lds,
                                       int mt, int nt, int tid) {
  const int slot0 = mt * 256;
  if (slot0 >= meta[M_TOT]) return;
  int e = 0;
#pragma unroll
  for (int i = 1; i < NEXP; ++i) e += (slot0 >= meta[8 + i]);
  if (tid == 0) spin_ge(&meta[M_DONE + mt], 8);
  __syncthreads();
  gemm_body<1024, false>(hbuf, w2 + (size_t)e * 2048 * 512,
                         w2s + (size_t)e * 2048 * 32, ys, lds, slot0, nt, tid);
}

// ---------------- static overlapped GEMM kernel (256 blocks, R11 schedule) ----------------
// __launch_bounds__(512, 1): LDS (128KB) caps at 1 block/CU regardless, and the
// (512,2) variant's 128-VGPR cap caused R15's scratch-spill catastrophe.
__global__ __launch_bounds__(512, 1) void gemm_static(
    const u16* __restrict__ xs, const int* __restrict__ w1,
    const float* __restrict__ w1s, const int* __restrict__ w2,
    const float* __restrict__ w2s, u16* __restrict__ hbuf, u16* __restrict__ ys,
    int* __restrict__ meta) {
  __shared__ u16 lds[2 * 32768];
  const int tid = threadIdx.x;
  const int b = blockIdx.x;

  run_g1(xs, w1, w1s, hbuf, meta, lds, b & 31, b >> 5, tid);
  if (b < 64) {
    run_g1(xs, w1, w1s, hbuf, meta, lds, 32 + (b & 7), b >> 3, tid);
    run_g2(hbuf, w2, w2s, ys, meta, lds, 32 + (b & 7), b >> 3, tid);
  } else {
    const int x = b & 7, q = (b - 64) >> 3;   // q in 0..23
    {
      const int k = q;
      run_g2(hbuf, w2, w2s, ys, meta, lds, x + 8 * (k & 3), k >> 2, tid);
    }
    if (q < 8) {
      const int k = q + 24;
      run_g2(hbuf, w2, w2s, ys, meta, lds, x + 8 * (k & 3), k >> 2, tid);
    }
  }
}

// ---------------- combine (slot-major ys via slotof) ----------------
__global__ void combine_k(const u16* __restrict__ ys, const float* __restrict__ ew,
                          const int* __restrict__ meta, float* __restrict__ out) {
  const int idx = blockIdx.x * 256 + threadIdx.x;
  const int t = idx >> 8;
  const int pos = (idx & 255) * 8;
  const int* slotof = meta + M_SLOTOF;
  const int s0 = slotof[t * 2];
  const int s1 = slotof[t * 2 + 1];
  const float w0 = ew[t * 2];
  const float w1 = ew[t * 2 + 1];
  const u16x8 v0 = *(const u16x8*)(ys + (size_t)s0 * HID + pos);
  const u16x8 v1 = *(const u16x8*)(ys + (size_t)s1 * HID + pos);
  float* dst = out + (size_t)t * HID + pos;
  float4 o0, o1;
  o0.x = w0 * bf2f(v0[0]) + w1 * bf2f(v1[0]);
  o0.y = w0 * bf2f(v0[1]) + w1 * bf2f(v1[1]);
  o0.z = w0 * bf2f(v0[2]) + w1 * bf2f(v1[2]);
  o0.w = w0 * bf2f(v0[3]) + w1 * bf2f(v1[3]);
  o1.x = w0 * bf2f(v0[4]) + w1 * bf2f(v1[4]);
  o1.y = w0 * bf2f(v0[5]) + w1 * bf2f(v1[5]);
  o1.z = w0 * bf2f(v0[6]) + w1 * bf2f(v1[6]);
  o1.w = w0 * bf2f(v0[7]) + w1 * bf2f(v1[7]);
  *(float4*)dst = o0;
  *(float4*)(dst + 4) = o1;
}

// ---------------- launch ----------------
extern "C" void kernel_launch(void* const* d_in, const int* in_sizes, int n_in,
                              void* d_out, int out_size, void* d_ws, size_t ws_size,
                              hipStream_t stream) {
  const float* x    = (const float*)d_in[0];
  const int*   w1   = (const int*)d_in[1];
  const float* w1s  = (const float*)d_in[2];
  const int*   w2   = (const int*)d_in[3];
  const float* w2s  = (const float*)d_in[4];
  const float* ew   = (const float*)d_in[5];
  const int*   eidx = (const int*)d_in[6];
  float* out = (float*)d_out;

  char* ws = (char*)d_ws;
  const size_t OFF_XS   = 0;          // 10240*2048*2 = 41,943,040 (xs; ys aliases)
  const size_t OFF_H    = 41943040;   // 10240*1024*2 = 20,971,520
  const size_t OFF_META = 62914560;   // pad 131,072
  const size_t NEED     = 63045632;
  if (ws_size < NEED) return;

  u16* xs   = (u16*)(ws + OFF_XS);    // slot-gathered activations; G2 output aliases
  u16* hbuf = (u16*)(ws + OFF_H);
  int* meta = (int*)(ws + OFF_META);

  router_count<<<1, 256, 0, stream>>>(eidx, meta);
  init_k<<<SLOT_CAP / 256, 256, 0, stream>>>(meta);
  router_assign<<<T_TOK / 256, 256, 0, stream>>>(eidx, meta);

  xprep_k<<<T_TOK, 256, 0, stream>>>(x, meta, xs);

  gemm_static<<<256, 512, 0, stream>>>(xs, w1, w1s, w2, w2s, hbuf, xs, meta);

  combine_k<<<(T_TOK * HID) / (256 * 8), 256, 0, stream>>>(xs, ew, meta, out);
}

// Round 17
// 251.737 us; speedup vs baseline: 1.7025x; 1.6821x over previous
//
#include <hip/hip_runtime.h>
#include <cstdint>
#include <cstddef>

typedef unsigned int u32;
typedef unsigned short u16;
typedef __bf16 bf16x8 __attribute__((ext_vector_type(8)));
typedef float f32x4 __attribute__((ext_vector_type(4)));
typedef u16 u16x8 __attribute__((ext_vector_type(8)));

static constexpr int T_TOK = 4096;
static constexpr int HID   = 2048;
static constexpr int INTER = 1024;
static constexpr int NEXP  = 8;
static constexpr int TOPK  = 2;
static constexpr int SLOT_CAP = 10240;   // 8192 real + per-expert 256-align pad
static constexpr int NT_M = 40;

// meta int indices
static constexpr int M_TOT  = 16;
static constexpr int M_CUR  = 17;   // 8 router cursors
static constexpr int M_DONE = 40;   // 40 per-mt done counters
static constexpr int M_TOK  = 96;   // toklist[SLOT_CAP], values t*2+k

__device__ __forceinline__ u16 f2bf(float f) {
  u32 u = __builtin_bit_cast(u32, f);
  u32 r = (u + 0x7fffu + ((u >> 16) & 1u)) >> 16;
  return (u16)r;
}
__device__ __forceinline__ float bf2f(u16 h) {
  return __builtin_bit_cast(float, (u32)h << 16);
}

// RELAXED poll (no per-iter L2 invalidate) + one acquire fence after success.
__device__ __forceinline__ void spin_ge(int* p, int target) {
  while (__hip_atomic_load(p, __ATOMIC_RELAXED, __HIP_MEMORY_SCOPE_AGENT) < target)
    __builtin_amdgcn_s_sleep(8);
  __builtin_amdgcn_fence(__ATOMIC_ACQUIRE, "agent");
}
// stores done -> __syncthreads() (drains all waves' vmcnt) -> tid0 release RMW.
__device__ __forceinline__ void bump(int* p, int tid) {
  __syncthreads();
  if (tid == 0)
    __hip_atomic_fetch_add(p, 1, __ATOMIC_RELEASE, __HIP_MEMORY_SCOPE_AGENT);
}

// ---------------- router ----------------
__global__ void router_count(const int* __restrict__ eidx, int* __restrict__ meta) {
  __shared__ int cnt[NEXP];
  const int tid = threadIdx.x;
  if (tid < NEXP) cnt[tid] = 0;
  __syncthreads();
  for (int i = tid; i < T_TOK * TOPK; i += 256) atomicAdd(&cnt[eidx[i]], 1);
  __syncthreads();
  if (tid == 0) {
    int off = 0;
    for (int e = 0; e < NEXP; ++e) {
      int c = cnt[e];
      meta[e] = c;
      meta[8 + e] = off;
      meta[M_CUR + e] = off;
      off += (c + 255) & ~255;      // 256-aligned regions (BM=256)
    }
    meta[M_TOT] = off;
  }
}

__global__ void init_k(int* __restrict__ meta) {
  const int i = blockIdx.x * 256 + threadIdx.x;
  if (i < SLOT_CAP) meta[M_TOK + i] = 0;   // pad rows gather token 0 (writes skipped)
  if (i >= 25 && i < 80) meta[i] = 0;      // DONE[40] etc.
}

__global__ void router_assign(const int* __restrict__ eidx, int* __restrict__ meta) {
  const int t = blockIdx.x * 256 + threadIdx.x;
  if (t >= T_TOK) return;
  int* cursors = meta + M_CUR;
  int* toklist = meta + M_TOK;
  for (int k = 0; k < TOPK; ++k) {
    const int e = eidx[t * TOPK + k];
    const int pos = atomicAdd(&cursors[e], 1);
    toklist[pos] = t * 2 + k;
  }
}

// ---------------- dequant helper (1 thread = 4 int32 -> 8 bf16) ----------------
template <int CPR>
__device__ __forceinline__ void deq1(const int* __restrict__ p, const float* __restrict__ s,
                                     u16* __restrict__ w, int gid) {
  const int row = gid / CPR;
  const int cid = gid % CPR;
  const int4 pk = *(const int4*)(p + (size_t)gid * 4);
  const float sc = s[(size_t)row * (CPR / 4) + (cid >> 2)];
  int v[4] = {pk.x, pk.y, pk.z, pk.w};
  u16x8 o;
#pragma unroll
  for (int b = 0; b < 4; ++b) {
    o[2 * b]     = f2bf((float)((v[b] & 15) - 8) * sc);
    o[2 * b + 1] = f2bf((float)(((v[b] >> 4) & 15) - 8) * sc);
  }
  *(u16x8*)(w + (size_t)gid * 8) = o;
}

// ---------------- merged prep: [0,16384) deqW1, [16384,24576) deqW2, [24576,28672) cast ----------------
__global__ void prep_k(const int* __restrict__ w1, const float* __restrict__ w1s,
                       const int* __restrict__ w2, const float* __restrict__ w2s,
                       const float* __restrict__ x, u16* __restrict__ W1b,
                       u16* __restrict__ W2b, u16* __restrict__ xb) {
  const int blk = blockIdx.x;
  if (blk < 16384) {
    deq1<256>(w1, w1s, W1b, blk * 256 + threadIdx.x);
  } else if (blk < 24576) {
    deq1<128>(w2, w2s, W2b, (blk - 16384) * 256 + threadIdx.x);
  } else {
    const int i = ((blk - 24576) * 256 + threadIdx.x) * 8;
    const float4 a = *(const float4*)(x + i);
    const float4 b = *(const float4*)(x + i + 4);
    u16x8 o;
    o[0] = f2bf(a.x); o[1] = f2bf(a.y); o[2] = f2bf(a.z); o[3] = f2bf(a.w);
    o[4] = f2bf(b.x); o[5] = f2bf(b.y); o[6] = f2bf(b.z); o[7] = f2bf(b.w);
    *(u16x8*)(xb + i) = o;
  }
}

// ---------------- 256x256 GEMM tile body (2-phase, conflict-free swizzle) ----------------
// C[slot, n] = sum_k A[row(slot), k] * B[n, k]  (B K-major). BM=BN=256, BK=64,
// 8 waves (2M x 4N), wave tile 128x64, dbuf LDS 2x64KB. Swizzle o^=((o>>7)&3)<<4
// (PMC-verified: SQ_LDS_BANK_CONFLICT = 0).
// G1M: gather A rows via toklist>>1, silu(gate)*up epilogue into hbuf[slot].
// !G1M: token-scatter epilogue into yt[toklist[slot]] (pad rows skipped via vend).
template <int KT, bool G1M>
__device__ void gemm_body(const u16* __restrict__ A, const u16* __restrict__ Be,
                          u16* __restrict__ Cout, const int* __restrict__ toklist,
                          int vend, u16* lds, int slot0, int nt, int tid) {
  static constexpr int NT = KT / 64;
  char* ldsB = (char*)lds;

  const u16* asrc[4];
  const u16* bsrc[4];
#pragma unroll
  for (int j = 0; j < 4; ++j) {
    const int L = j * 8192 + tid * 16;
    const int S = L >> 10;
    int o = L & 1023;
    o ^= ((o >> 7) & 3) << 4;
    const int r = (S >> 1) * 16 + (o >> 6);
    const int cb = (S & 1) * 64 + (o & 63);
    const int arow = G1M ? (toklist[slot0 + r] >> 1) : (slot0 + r);
    asrc[j] = A + (size_t)arow * KT + (cb >> 1);
    int brow;
    if (G1M) {
      const int g = r >> 6, j6 = r & 63;
      brow = nt * 128 + g * 32 + (j6 & 31) + ((j6 >> 5) << 10);  // gate | up+1024
    } else {
      brow = nt * 256 + r;
    }
    bsrc[j] = Be + (size_t)brow * KT + (cb >> 1);
  }

#define STAGE(kt_, c_)                                                                \
  do {                                                                                \
    char* dA_ = ldsB + (c_) * 65536;                                                  \
    char* dB_ = dA_ + 32768;                                                          \
    _Pragma("unroll") for (int j = 0; j < 4; ++j)                                     \
        __builtin_amdgcn_global_load_lds(                                             \
            (const __attribute__((address_space(1))) void*)(asrc[j] + (kt_) * 64),    \
            (__attribute__((address_space(3))) void*)(dA_ + j * 8192 + tid * 16),     \
            16, 0, 0);                                                                \
    _Pragma("unroll") for (int j = 0; j < 4; ++j)                                     \
        __builtin_amdgcn_global_load_lds(                                             \
            (const __attribute__((address_space(1))) void*)(bsrc[j] + (kt_) * 64),    \
            (__attribute__((address_space(3))) void*)(dB_ + j * 8192 + tid * 16),     \
            16, 0, 0);                                                                \
  } while (0)

  const int lane = tid & 63;
  const int wid = tid >> 6;
  const int wm = (wid >> 2) * 128;
  const int wn = (wid & 3) * 64;
  const int fr = lane & 15;
  const int qq = lane >> 4;
  const int swz = (qq * 16) ^ (((fr >> 1) & 3) << 4);

  const int abase = (wm >> 4) * 2048 + fr * 64 + swz;
  const int bbase = 32768 + (wn >> 4) * 2048 + fr * 64 + swz;

  f32x4 acc[8][4];
#pragma unroll
  for (int m = 0; m < 8; ++m)
#pragma unroll
    for (int n = 0; n < 4; ++n) acc[m][n] = (f32x4)0.0f;

#define COMPUTE(c_)                                                                   \
  do {                                                                                \
    const char* bb_ = ldsB + (c_) * 65536;                                            \
    bf16x8 bfr_[4][2];                                                                \
    _Pragma("unroll") for (int nf = 0; nf < 4; ++nf)                                  \
        _Pragma("unroll") for (int ks = 0; ks < 2; ++ks)                              \
            bfr_[nf][ks] = *(const bf16x8*)(bb_ + bbase + nf * 2048 + ks * 1024);     \
    _Pragma("unroll") for (int mh = 0; mh < 2; ++mh) {                                \
      bf16x8 af_[4][2];                                                               \
      _Pragma("unroll") for (int mf = 0; mf < 4; ++mf)                                \
          _Pragma("unroll") for (int ks = 0; ks < 2; ++ks)                            \
              af_[mf][ks] = *(const bf16x8*)(bb_ + abase + mh * 8192 + mf * 2048 +    \
                                             ks * 1024);                              \
      __builtin_amdgcn_s_setprio(1);                                                  \
      _Pragma("unroll") for (int mf = 0; mf < 4; ++mf)                                \
          _Pragma("unroll") for (int nf = 0; nf < 4; ++nf)                            \
              _Pragma("unroll") for (int ks = 0; ks < 2; ++ks)                        \
                  acc[mh * 4 + mf][nf] = __builtin_amdgcn_mfma_f32_16x16x32_bf16(     \
                      af_[mf][ks], bfr_[nf][ks], acc[mh * 4 + mf][nf], 0, 0, 0);      \
      __builtin_amdgcn_s_setprio(0);                                                  \
    }                                                                                 \
  } while (0)

  STAGE(0, 0);
#pragma unroll 1
  for (int kt = 0; kt < NT; kt += 2) {
    asm volatile("s_waitcnt vmcnt(0)" ::: "memory");
    __builtin_amdgcn_s_barrier();
    __builtin_amdgcn_sched_barrier(0);
    if (kt + 1 < NT) STAGE(kt + 1, 1);
    COMPUTE(0);
    asm volatile("s_waitcnt vmcnt(0)" ::: "memory");
    __builtin_amdgcn_s_barrier();
    __builtin_amdgcn_sched_barrier(0);
    if (kt + 2 < NT) STAGE(kt + 2, 0);
    COMPUTE(1);
  }
#undef STAGE
#undef COMPUTE

  // epilogue: C/D layout col=lane&15, row=(lane>>4)*4+j  [m89-verified]
  if (G1M) {
    const int g = wid & 3;
#pragma unroll
    for (int mi = 0; mi < 8; ++mi)
#pragma unroll
      for (int n = 0; n < 2; ++n)
#pragma unroll
        for (int jj = 0; jj < 4; ++jj) {
          const float gv = acc[mi][n][jj];
          const float uv = acc[mi][n + 2][jj];
          const float hv = gv / (1.0f + __expf(-gv)) * uv;
          const int row = slot0 + wm + mi * 16 + qq * 4 + jj;
          Cout[(size_t)row * INTER + nt * 128 + g * 32 + n * 16 + fr] = f2bf(hv);
        }
  } else {
    // token-scatter: yt[toklist[slot]][col]; skip pad rows (slot >= vend)
#pragma unroll
    for (int mi = 0; mi < 8; ++mi)
#pragma unroll
      for (int jj = 0; jj < 4; ++jj) {
        const int slot = slot0 + wm + mi * 16 + qq * 4 + jj;
        if (slot < vend) {
          const int tk = toklist[slot];
          const int col = nt * 256 + wn + fr;
#pragma unroll
          for (int n = 0; n < 4; ++n)
            Cout[(size_t)tk * HID + col + n * 16] = f2bf(acc[mi][n][jj]);
        }
      }
  }
}

// ---------------- static-schedule tile runners ----------------
__device__ __forceinline__ void run_g1(const u16* xb, const u16* W1b, u16* hbuf,
                                       int* meta, const int* toklist, u16* lds,
                                       int mt, int nt, int tid) {
  const int slot0 = mt * 256;
  if (slot0 < meta[M_TOT]) {
    int e = 0;
#pragma unroll
    for (int i = 1; i < NEXP; ++i) e += (slot0 >= meta[8 + i]);
    gemm_body<2048, true>(xb, W1b + (size_t)e * 2048 * 2048, hbuf, toklist, 0,
                          lds, slot0, nt, tid);
  }
  bump(&meta[M_DONE + mt], tid);   // bump even when skipped so spins reach 8
}

__device__ __forceinline__ void run_g2(const u16* hbuf, const u16* W2b, u16* yt,
                                       int* meta, const int* toklist, u16* lds,
                                       int mt, int nt, int tid) {
  const int slot0 = mt * 256;
  if (slot0 >= meta[M_TOT]) return;
  int e = 0;
#pragma unroll
  for (int i = 1; i < NEXP; ++i) e += (slot0 >= meta[8 + i]);
  if (tid == 0) spin_ge(&meta[M_DONE + mt], 8);
  __syncthreads();
  const int vend = meta[8 + e] + meta[e];
  gemm_body<1024, false>(hbuf, W2b + (size_t)e * 2048 * 1024, yt, toklist, vend,
                         lds, slot0, nt, tid);
}

// ---------------- static overlapped GEMM kernel (256 blocks) ----------------
// G1 round 1: block b -> (mt=b%32, nt=b/32); same-mt blocks on XCD mt%8.
// G1 round 2: blocks 0..63 -> (mt=32+b%8, nt=b/8).
// G2: blocks 64..255 take the 256 tiles of mts 0..31 (mt%8==b%8 keeps hbuf
//     L2-local); blocks 0..63 take G2 of mts 32..39 after their own G1.
__global__ __launch_bounds__(512, 2) void gemm_static(
    const u16* __restrict__ xb, const u16* __restrict__ W1b,
    const u16* __restrict__ W2b, u16* __restrict__ hbuf, u16* __restrict__ yt,
    int* __restrict__ meta) {
  __shared__ u16 lds[2 * 32768];
  const int tid = threadIdx.x;
  const int b = blockIdx.x;
  const int* toklist = meta + M_TOK;

  run_g1(xb, W1b, hbuf, meta, toklist, lds, b & 31, b >> 5, tid);
  if (b < 64) {
    run_g1(xb, W1b, hbuf, meta, toklist, lds, 32 + (b & 7), b >> 3, tid);
    run_g2(hbuf, W2b, yt, meta, toklist, lds, 32 + (b & 7), b >> 3, tid);
  } else {
    const int x = b & 7, q = (b - 64) >> 3;   // q in 0..23
    {
      const int k = q;
      run_g2(hbuf, W2b, yt, meta, toklist, lds, x + 8 * (k & 3), k >> 2, tid);
    }
    if (q < 8) {
      const int k = q + 24;
      run_g2(hbuf, W2b, yt, meta, toklist, lds, x + 8 * (k & 3), k >> 2, tid);
    }
  }
}

// ---------------- combine (token-major yt: rows 2t, 2t+1) ----------------
__global__ void combine_k(const u16* __restrict__ yt, const float* __restrict__ ew,
                          float* __restrict__ out) {
  const int idx = blockIdx.x * 256 + threadIdx.x;
  const int t = idx >> 8;
  const int pos = (idx & 255) * 8;
  const float w0 = ew[t * 2];
  const float w1 = ew[t * 2 + 1];
  const u16x8 v0 = *(const u16x8*)(yt + (size_t)(t * 2) * HID + pos);
  const u16x8 v1 = *(const u16x8*)(yt + (size_t)(t * 2 + 1) * HID + pos);
  float* dst = out + (size_t)t * HID + pos;
  float4 o0, o1;
  o0.x = w0 * bf2f(v0[0]) + w1 * bf2f(v1[0]);
  o0.y = w0 * bf2f(v0[1]) + w1 * bf2f(v1[1]);
  o0.z = w0 * bf2f(v0[2]) + w1 * bf2f(v1[2]);
  o0.w = w0 * bf2f(v0[3]) + w1 * bf2f(v1[3]);
  o1.x = w0 * bf2f(v0[4]) + w1 * bf2f(v1[4]);
  o1.y = w0 * bf2f(v0[5]) + w1 * bf2f(v1[5]);
  o1.z = w0 * bf2f(v0[6]) + w1 * bf2f(v1[6]);
  o1.w = w0 * bf2f(v0[7]) + w1 * bf2f(v1[7]);
  *(float4*)dst = o0;
  *(float4*)(dst + 4) = o1;
}

// ---------------- launch ----------------
extern "C" void kernel_launch(void* const* d_in, const int* in_sizes, int n_in,
                              void* d_out, int out_size, void* d_ws, size_t ws_size,
                              hipStream_t stream) {
  const float* x    = (const float*)d_in[0];
  const int*   w1   = (const int*)d_in[1];
  const float* w1s  = (const float*)d_in[2];
  const int*   w2   = (const int*)d_in[3];
  const float* w2s  = (const float*)d_in[4];
  const float* ew   = (const float*)d_in[5];
  const int*   eidx = (const int*)d_in[6];
  float* out = (float*)d_out;

  char* ws = (char*)d_ws;
  const size_t OFF_W1B  = 0;           // 67,108,864
  const size_t OFF_W2B  = 67108864;    // 33,554,432
  const size_t OFF_XB   = 100663296;   // 16,777,216
  const size_t OFF_H    = 117440512;   // 20,971,520
  const size_t OFF_YT   = 138412032;   // 8192*2048*2 = 33,554,432 (token-major)
  const size_t OFF_META = 171966464;   // pad to 76,800
  const size_t NEED     = 172043264;   // < 174,133,376 proven available (R1)
  if (ws_size < NEED) return;

  u16* W1b  = (u16*)(ws + OFF_W1B);
  u16* W2b  = (u16*)(ws + OFF_W2B);
  u16* xb   = (u16*)(ws + OFF_XB);
  u16* hbuf = (u16*)(ws + OFF_H);
  u16* yt   = (u16*)(ws + OFF_YT);
  int* meta = (int*)(ws + OFF_META);

  router_count<<<1, 256, 0, stream>>>(eidx, meta);
  init_k<<<SLOT_CAP / 256, 256, 0, stream>>>(meta);
  router_assign<<<T_TOK / 256, 256, 0, stream>>>(eidx, meta);

  prep_k<<<28672, 256, 0, stream>>>(w1, w1s, w2, w2s, x, W1b, W2b, xb);

  gemm_static<<<256, 512, 0, stream>>>(xb, W1b, W2b, hbuf, yt, meta);

  combine_k<<<(T_TOK * HID) / (256 * 8), 256, 0, stream>>>(yt, ew, out);
}